// Round 21
// baseline (32.015 us; speedup 1.0000x reference)
//
#include <hip/hip_runtime.h>
#include <math.h>

#define BATCH 4
#define NPTS  8192
#define TOTAL (BATCH * NPTS)            // 32768 points per set
#define TPB   256

#define CT     2                        // fixed col-tiles per wave (32 cols each)
#define WPB    (TPB / 64)               // 4 waves per block
#define COLS_PER_WAVE  (32 * CT)        // 64
#define COLS_PER_BLOCK (COLS_PER_WAVE * WPB)  // 256
#define ROWCH  16                       // swept-row chunks
#define SWEEP  (NPTS / ROWCH)           // 512 rows swept per wave
#define NT     (SWEEP / 32)             // 16 A-tiles per sweep
#define NCH    (NT / 4)                 // 4 chunks of 4 tiles

typedef __bf16 bf16v8 __attribute__((ext_vector_type(8)));
typedef float  f32x16 __attribute__((ext_vector_type(16)));

// ws layout (TILE-MAJOR, MFMA-LANE-ORDER packing; tile = 512 ushorts = 1KB):
//   Af: ushort[2*TOTAL*16] @ 0    (2 MB)  set1 then set2
//   Bf: ushort[2*TOTAL*16] @ 2 MB (2 MB)  same layout
//   minbuf: uint[2*TOTAL]  @ 4 MB (256 KB) dist1 then dist2
//   (chunk prefetch over-reads <=4KB past the A region into Bf -- mapped, dead)

__device__ __forceinline__ unsigned f2ord(float f) {
  unsigned b = __float_as_uint(f);
  return ((int)b >= 0) ? (b ^ 0x80000000u) : ~b;
}
__device__ __forceinline__ float ord2f(unsigned k) {
  unsigned b = (k & 0x80000000u) ? (k ^ 0x80000000u) : ~k;
  return __uint_as_float(b);
}
__device__ __forceinline__ unsigned short f2bf(float f) {   // RNE
  unsigned u = __float_as_uint(f);
  return (unsigned short)((u + 0x7fffu + ((u >> 16) & 1u)) >> 16);
}
__device__ __forceinline__ float bf2f(unsigned short h) {
  return __uint_as_float(((unsigned)h) << 16);
}
__device__ __forceinline__ float mf3(float a, float b, float c) {
  return fminf(fminf(a, b), c);   // ISel fuses to v_min3_f32
}
__device__ __forceinline__ float coltree(const f32x16& a, float colt) {
  float t0 = mf3(a[0], a[1], a[2]);
  float t1 = mf3(a[3], a[4], a[5]);
  float t2 = mf3(a[6], a[7], a[8]);
  float t3 = mf3(a[9], a[10], a[11]);
  float t4 = mf3(a[12], a[13], a[14]);
  return mf3(colt, mf3(t0, t1, a[15]), mf3(t2, t3, t4));
}

// K-slot pairing (A[k]*B[k]), verified absmax 0 since R4:
//  k0-2: ah*ch   k3-5: al*ch   k6-8: ah*cl   (c = -2b)
//  k9,10: sq_a{h,l} * 1,1      k11,12: 1,1 * sq_b{h,l}     k13-15: 0
__global__ __launch_bounds__(TPB) void pack_kernel(
    const float* __restrict__ x1, const float* __restrict__ x2,
    unsigned short* __restrict__ Af, unsigned short* __restrict__ Bf,
    unsigned* __restrict__ minbuf, float* __restrict__ out) {
  int i = blockIdx.x * TPB + threadIdx.x;   // 0 .. 2*TOTAL-1  (set-major)
  if (i == 0) out[0] = 0.0f;
  minbuf[i] = 0xFFFFFFFFu;

  bool s2 = (i >= TOTAL);
  int j = s2 ? i - TOTAL : i;
  const float* src = s2 ? x2 : x1;
  float x = src[3 * j + 0];
  float y = src[3 * j + 1];
  float z = src[3 * j + 2];
  float sq = fmaf(x, x, fmaf(y, y, z * z));
  unsigned short sh = f2bf(sq);
  unsigned short sl = f2bf(sq - bf2f(sh));
  const unsigned short one = 0x3F80;

  unsigned short hx = f2bf(x), hy = f2bf(y), hz = f2bf(z);
  unsigned short lx = f2bf(x - bf2f(hx)), ly = f2bf(y - bf2f(hy)), lz = f2bf(z - bf2f(hz));
  float cx = -2.0f * x, cy = -2.0f * y, cz = -2.0f * z;
  unsigned short chx = f2bf(cx), chy = f2bf(cy), chz = f2bf(cz);
  unsigned short clx = f2bf(cx - bf2f(chx)), cly = f2bf(cy - bf2f(chy)), clz = f2bf(cz - bf2f(chz));

  // tile-major lane-order offsets (ushort units), tile stride 512:
  size_t o0 = (size_t)(i >> 5) * 512 + (size_t)(i & 31) * 8;
  size_t o1 = o0 + 256;

  // A-form
  {
    unsigned short v[16] = {hx, hy, hz, lx, ly, lz, hx, hy, hz,
                            sh, sl, one, one, 0, 0, 0};
    uint4 w0, w1;
    w0.x = v[0] | ((unsigned)v[1] << 16);  w0.y = v[2] | ((unsigned)v[3] << 16);
    w0.z = v[4] | ((unsigned)v[5] << 16);  w0.w = v[6] | ((unsigned)v[7] << 16);
    w1.x = v[8] | ((unsigned)v[9] << 16);  w1.y = v[10] | ((unsigned)v[11] << 16);
    w1.z = v[12] | ((unsigned)v[13] << 16); w1.w = v[14] | ((unsigned)v[15] << 16);
    *(uint4*)(Af + o0) = w0;
    *(uint4*)(Af + o1) = w1;
  }
  // B-form
  {
    unsigned short v[16] = {chx, chy, chz, chx, chy, chz, clx, cly, clz,
                            one, one, sh, sl, 0, 0, 0};
    uint4 w0, w1;
    w0.x = v[0] | ((unsigned)v[1] << 16);  w0.y = v[2] | ((unsigned)v[3] << 16);
    w0.z = v[4] | ((unsigned)v[5] << 16);  w0.w = v[6] | ((unsigned)v[7] << 16);
    w1.x = v[8] | ((unsigned)v[9] << 16);  w1.y = v[10] | ((unsigned)v[11] << 16);
    w1.z = v[12] | ((unsigned)v[13] << 16); w1.w = v[14] | ((unsigned)v[15] << 16);
    *(uint4*)(Bf + o0) = w0;
    *(uint4*)(Bf + o1) = w1;
  }
}

// Col-min-only pass, both directions via blockIdx.z. R21 = R20 champion
// with PRESSURE-BALANCED chunked pipeline: 4-tile chunks, double-buffered
// staged loads (8 in flight). Live regs ~100 < 128 cap -> MFMA accs can
// stay arch-VGPR (v_min3 reads them directly, no accvgpr copies), while
// prefetch depth 8 still covers L2 latency. (R15's 16-deep staging blew
// the budget -> AGPR accs; R18's 4-deep had no latency cover.)
__global__ __launch_bounds__(TPB, 4) void min_kernel(
    const unsigned short* __restrict__ Af, const unsigned short* __restrict__ Bf,
    unsigned* __restrict__ minbuf) {
  const int z   = blockIdx.z;
  const int b   = z & (BATCH - 1);
  const int dir = z >> 2;
  const int tid = threadIdx.x;
  const int wave = tid >> 6, lane = tid & 63;
  const int g = lane >> 5, l31 = lane & 31;

  const int colset = dir * TOTAL;          // offset of the col (target) set
  const int rowset = TOTAL - colset;       // offset of the swept set
  const int colbase = blockIdx.x * COLS_PER_BLOCK + wave * COLS_PER_WAVE;
  const int rowbase = blockIdx.y * SWEEP;

  // fixed B fragments: CT=2 col-tiles, lane-sequential (tile = 64 bf16v8)
  const int bt0 = (colset + b * NPTS + colbase) >> 5;
  const bf16v8* bvt = (const bf16v8*)Bf;
  bf16v8 bfr0 = bvt[(size_t)bt0 * 64 + lane];
  bf16v8 bfr1 = bvt[(size_t)(bt0 + 1) * 64 + lane];

  f32x16 zc;
#pragma unroll
  for (int q = 0; q < 16; ++q) zc[q] = 0.0f;
  float colacc0 = INFINITY, colacc1 = INFINITY;

  const int at0 = (rowset + b * NPTS + rowbase) >> 5;
  const bf16v8* ap = (const bf16v8*)Af + (size_t)at0 * 64 + lane;

  // prologue: stage chunk 0
  bf16v8 s0 = ap[0], s1 = ap[64], s2 = ap[128], s3 = ap[192];
  for (int c = 0; c < NCH; ++c) {
    // issue next chunk's loads (unconditional; tail over-read <=4KB, mapped)
    bf16v8 n0 = ap[256], n1 = ap[320], n2 = ap[384], n3 = ap[448];

    f32x16 a0 = __builtin_amdgcn_mfma_f32_32x32x16_bf16(s0, bfr0, zc, 0, 0, 0);
    f32x16 a1 = __builtin_amdgcn_mfma_f32_32x32x16_bf16(s0, bfr1, zc, 0, 0, 0);
    colacc0 = coltree(a0, colacc0);
    colacc1 = coltree(a1, colacc1);
    a0 = __builtin_amdgcn_mfma_f32_32x32x16_bf16(s1, bfr0, zc, 0, 0, 0);
    a1 = __builtin_amdgcn_mfma_f32_32x32x16_bf16(s1, bfr1, zc, 0, 0, 0);
    colacc0 = coltree(a0, colacc0);
    colacc1 = coltree(a1, colacc1);
    a0 = __builtin_amdgcn_mfma_f32_32x32x16_bf16(s2, bfr0, zc, 0, 0, 0);
    a1 = __builtin_amdgcn_mfma_f32_32x32x16_bf16(s2, bfr1, zc, 0, 0, 0);
    colacc0 = coltree(a0, colacc0);
    colacc1 = coltree(a1, colacc1);
    a0 = __builtin_amdgcn_mfma_f32_32x32x16_bf16(s3, bfr0, zc, 0, 0, 0);
    a1 = __builtin_amdgcn_mfma_f32_32x32x16_bf16(s3, bfr1, zc, 0, 0, 0);
    colacc0 = coltree(a0, colacc0);
    colacc1 = coltree(a1, colacc1);

    s0 = n0; s1 = n1; s2 = n2; s3 = n3;
    ap += 256;
  }

  // tail: merge g-halves, one masked atomic per tile
  {
    float m0 = fminf(colacc0, __shfl_xor(colacc0, 32));
    float m1 = fminf(colacc1, __shfl_xor(colacc1, 32));
    if (g == 0) {
      atomicMin(&minbuf[colset + b * NPTS + colbase + l31], f2ord(m0));
      atomicMin(&minbuf[colset + b * NPTS + colbase + 32 + l31], f2ord(m1));
    }
  }
}

__global__ __launch_bounds__(TPB) void finalize_kernel(
    const unsigned* __restrict__ minbuf, float* __restrict__ out, float scale) {
  int idx = blockIdx.x * TPB + threadIdx.x;   // 0 .. 2*TOTAL-1
  float v = ord2f(minbuf[idx]) * scale;
  for (int off = 32; off > 0; off >>= 1) v += __shfl_down(v, off);
  __shared__ float ls[TPB / 64];
  if ((threadIdx.x & 63) == 0) ls[threadIdx.x >> 6] = v;
  __syncthreads();
  if (threadIdx.x == 0) {
    float t = 0.0f;
#pragma unroll
    for (int w = 0; w < TPB / 64; ++w) t += ls[w];
    atomicAdd(out, t);
  }
}

extern "C" void kernel_launch(void* const* d_in, const int* in_sizes, int n_in,
                              void* d_out, int out_size, void* d_ws, size_t ws_size,
                              hipStream_t stream) {
  const float* xyz1 = (const float*)d_in[0];
  const float* xyz2 = (const float*)d_in[1];
  float* out = (float*)d_out;

  char* ws = (char*)d_ws;
  unsigned short* Af = (unsigned short*)(ws);
  unsigned short* Bf = (unsigned short*)(ws + (size_t)2 * TOTAL * 32);
  unsigned*   minbuf = (unsigned*)(ws + (size_t)4 * TOTAL * 32);

  // 1) pack A/B forms for both sets (tile-major lane order) + init minbuf
  pack_kernel<<<dim3(2 * TOTAL / TPB), dim3(TPB), 0, stream>>>(
      xyz1, xyz2, Af, Bf, minbuf, out);

  // 2) both directions, col-min only: 32 x 16 x 8 = 4096 blocks
  dim3 mgrid(NPTS / COLS_PER_BLOCK, ROWCH, 2 * BATCH);
  min_kernel<<<mgrid, dim3(TPB), 0, stream>>>(Af, Bf, minbuf);

  // 3) finalize: mean(dist1) + mean(dist2)
  const float scale = 1.0f / (float)TOTAL;
  finalize_kernel<<<dim3(2 * TOTAL / TPB), dim3(TPB), 0, stream>>>(minbuf, out, scale);
}

// Round 22
// 30.941 us; speedup vs baseline: 1.0347x; 1.0347x over previous
//
#include <hip/hip_runtime.h>
#include <math.h>

#define BATCH 4
#define NPTS  8192
#define TOTAL (BATCH * NPTS)            // 32768 points per set
#define TPB   256

#define CT     2                        // fixed col-tiles per wave (32 cols each)
#define WPB    (TPB / 64)               // 4 waves per block
#define COLS_PER_WAVE  (32 * CT)        // 64
#define COLS_PER_BLOCK (COLS_PER_WAVE * WPB)  // 256
#define ROWCH  16                       // swept-row chunks
#define SWEEP  (NPTS / ROWCH)           // 512 rows swept per wave
#define NT     (SWEEP / 32)             // 16 A-tiles per sweep

typedef __bf16 bf16v8 __attribute__((ext_vector_type(8)));
typedef float  f32x16 __attribute__((ext_vector_type(16)));

// ws layout (TILE-MAJOR, MFMA-LANE-ORDER packing; tile = 512 ushorts = 1KB):
//   Af: ushort[2*TOTAL*16] @ 0    (2 MB)  set1 then set2
//   Bf: ushort[2*TOTAL*16] @ 2 MB (2 MB)  same layout
//   minbuf: uint[2*TOTAL]  @ 4 MB (256 KB) dist1 then dist2

__device__ __forceinline__ unsigned f2ord(float f) {
  unsigned b = __float_as_uint(f);
  return ((int)b >= 0) ? (b ^ 0x80000000u) : ~b;
}
__device__ __forceinline__ float ord2f(unsigned k) {
  unsigned b = (k & 0x80000000u) ? (k ^ 0x80000000u) : ~k;
  return __uint_as_float(b);
}
__device__ __forceinline__ unsigned short f2bf(float f) {   // RNE
  unsigned u = __float_as_uint(f);
  return (unsigned short)((u + 0x7fffu + ((u >> 16) & 1u)) >> 16);
}
__device__ __forceinline__ float bf2f(unsigned short h) {
  return __uint_as_float(((unsigned)h) << 16);
}
// min3-shaped fminf nesting (ISel fuses to v_min3_f32)
__device__ __forceinline__ float mf3(float a, float b, float c) {
  return fminf(fminf(a, b), c);
}
// min over 16 acc elements folded with carry-in (8 x v_min3)
__device__ __forceinline__ float coltree(const f32x16& a, float colt) {
  float t0 = mf3(a[0], a[1], a[2]);
  float t1 = mf3(a[3], a[4], a[5]);
  float t2 = mf3(a[6], a[7], a[8]);
  float t3 = mf3(a[9], a[10], a[11]);
  float t4 = mf3(a[12], a[13], a[14]);
  return mf3(colt, mf3(t0, t1, a[15]), mf3(t2, t3, t4));
}

// K-slot pairing (A[k]*B[k]), verified absmax 0 since R4:
//  k0-2: ah*ch   k3-5: al*ch   k6-8: ah*cl   (c = -2b)
//  k9,10: sq_a{h,l} * 1,1      k11,12: 1,1 * sq_b{h,l}     k13-15: 0
__global__ __launch_bounds__(TPB) void pack_kernel(
    const float* __restrict__ x1, const float* __restrict__ x2,
    unsigned short* __restrict__ Af, unsigned short* __restrict__ Bf,
    unsigned* __restrict__ minbuf, float* __restrict__ out) {
  int i = blockIdx.x * TPB + threadIdx.x;   // 0 .. 2*TOTAL-1  (set-major)
  if (i == 0) out[0] = 0.0f;
  minbuf[i] = 0xFFFFFFFFu;

  bool s2 = (i >= TOTAL);
  int j = s2 ? i - TOTAL : i;
  const float* src = s2 ? x2 : x1;
  float x = src[3 * j + 0];
  float y = src[3 * j + 1];
  float z = src[3 * j + 2];
  float sq = fmaf(x, x, fmaf(y, y, z * z));
  unsigned short sh = f2bf(sq);
  unsigned short sl = f2bf(sq - bf2f(sh));
  const unsigned short one = 0x3F80;

  unsigned short hx = f2bf(x), hy = f2bf(y), hz = f2bf(z);
  unsigned short lx = f2bf(x - bf2f(hx)), ly = f2bf(y - bf2f(hy)), lz = f2bf(z - bf2f(hz));
  float cx = -2.0f * x, cy = -2.0f * y, cz = -2.0f * z;
  unsigned short chx = f2bf(cx), chy = f2bf(cy), chz = f2bf(cz);
  unsigned short clx = f2bf(cx - bf2f(chx)), cly = f2bf(cy - bf2f(chy)), clz = f2bf(cz - bf2f(chz));

  // tile-major lane-order offsets (ushort units), tile stride 512:
  size_t o0 = (size_t)(i >> 5) * 512 + (size_t)(i & 31) * 8;
  size_t o1 = o0 + 256;

  // A-form
  {
    unsigned short v[16] = {hx, hy, hz, lx, ly, lz, hx, hy, hz,
                            sh, sl, one, one, 0, 0, 0};
    uint4 w0, w1;
    w0.x = v[0] | ((unsigned)v[1] << 16);  w0.y = v[2] | ((unsigned)v[3] << 16);
    w0.z = v[4] | ((unsigned)v[5] << 16);  w0.w = v[6] | ((unsigned)v[7] << 16);
    w1.x = v[8] | ((unsigned)v[9] << 16);  w1.y = v[10] | ((unsigned)v[11] << 16);
    w1.z = v[12] | ((unsigned)v[13] << 16); w1.w = v[14] | ((unsigned)v[15] << 16);
    *(uint4*)(Af + o0) = w0;
    *(uint4*)(Af + o1) = w1;
  }
  // B-form
  {
    unsigned short v[16] = {chx, chy, chz, chx, chy, chz, clx, cly, clz,
                            one, one, sh, sl, 0, 0, 0};
    uint4 w0, w1;
    w0.x = v[0] | ((unsigned)v[1] << 16);  w0.y = v[2] | ((unsigned)v[3] << 16);
    w0.z = v[4] | ((unsigned)v[5] << 16);  w0.w = v[6] | ((unsigned)v[7] << 16);
    w1.x = v[8] | ((unsigned)v[9] << 16);  w1.y = v[10] | ((unsigned)v[11] << 16);
    w1.z = v[12] | ((unsigned)v[13] << 16); w1.w = v[14] | ((unsigned)v[15] << 16);
    *(uint4*)(Bf + o0) = w0;
    *(uint4*)(Bf + o1) = w1;
  }
}

// Col-min-only pass, both directions via blockIdx.z. R22 = R20 champion +
// PING-PONG MFMA PIPELINE: tile t+1's two MFMAs issue BEFORE tile t's
// coltrees, so the 16 min3 execute under the ~32-cyc matrix latency
// (R10 showed MfmaUtil+VALUBusy = 99% additive -> pipes were serialized;
// m114 says they CAN overlap). Alternating named acc pairs, full unroll,
// no register copies. Live ~115 regs < 128 cap -> accs stay VGPR-class.
__global__ __launch_bounds__(TPB, 4) void min_kernel(
    const unsigned short* __restrict__ Af, const unsigned short* __restrict__ Bf,
    unsigned* __restrict__ minbuf) {
  const int z   = blockIdx.z;
  const int b   = z & (BATCH - 1);
  const int dir = z >> 2;
  const int tid = threadIdx.x;
  const int wave = tid >> 6, lane = tid & 63;
  const int g = lane >> 5, l31 = lane & 31;

  const int colset = dir * TOTAL;          // offset of the col (target) set
  const int rowset = TOTAL - colset;       // offset of the swept set
  const int colbase = blockIdx.x * COLS_PER_BLOCK + wave * COLS_PER_WAVE;
  const int rowbase = blockIdx.y * SWEEP;

  // fixed B fragments: CT=2 col-tiles, lane-sequential (tile = 64 bf16v8)
  const int bt0 = (colset + b * NPTS + colbase) >> 5;
  const bf16v8* bvt = (const bf16v8*)Bf;
  bf16v8 bfr0 = bvt[(size_t)bt0 * 64 + lane];
  bf16v8 bfr1 = bvt[(size_t)(bt0 + 1) * 64 + lane];

  f32x16 zc;
#pragma unroll
  for (int q = 0; q < 16; ++q) zc[q] = 0.0f;
  float colacc0 = INFINITY, colacc1 = INFINITY;

  const int at0 = (rowset + b * NPTS + rowbase) >> 5;
  const bf16v8* ap = (const bf16v8*)Af + (size_t)at0 * 64 + lane;

  f32x16 pA, pB, cA, cB;
  {
    bf16v8 s = ap[0];
    pA = __builtin_amdgcn_mfma_f32_32x32x16_bf16(s, bfr0, zc, 0, 0, 0);
    pB = __builtin_amdgcn_mfma_f32_32x32x16_bf16(s, bfr1, zc, 0, 0, 0);
  }
#pragma unroll
  for (int k = 0; k < NT / 2 - 1; ++k) {   // k=0..6 -> tiles 1..14
    {
      bf16v8 s = ap[(2 * k + 1) * 64];
      cA = __builtin_amdgcn_mfma_f32_32x32x16_bf16(s, bfr0, zc, 0, 0, 0);
      cB = __builtin_amdgcn_mfma_f32_32x32x16_bf16(s, bfr1, zc, 0, 0, 0);
    }
    colacc0 = coltree(pA, colacc0);        // fold tile 2k under tile 2k+1's MFMA
    colacc1 = coltree(pB, colacc1);
    {
      bf16v8 s = ap[(2 * k + 2) * 64];
      pA = __builtin_amdgcn_mfma_f32_32x32x16_bf16(s, bfr0, zc, 0, 0, 0);
      pB = __builtin_amdgcn_mfma_f32_32x32x16_bf16(s, bfr1, zc, 0, 0, 0);
    }
    colacc0 = coltree(cA, colacc0);        // fold tile 2k+1 under 2k+2's MFMA
    colacc1 = coltree(cB, colacc1);
  }
  {
    bf16v8 s = ap[(NT - 1) * 64];          // tile 15
    cA = __builtin_amdgcn_mfma_f32_32x32x16_bf16(s, bfr0, zc, 0, 0, 0);
    cB = __builtin_amdgcn_mfma_f32_32x32x16_bf16(s, bfr1, zc, 0, 0, 0);
  }
  colacc0 = coltree(pA, colacc0);          // drain tiles 14, 15
  colacc1 = coltree(pB, colacc1);
  colacc0 = coltree(cA, colacc0);
  colacc1 = coltree(cB, colacc1);

  // tail: merge g-halves, one masked atomic per tile
  {
    float m0 = fminf(colacc0, __shfl_xor(colacc0, 32));
    float m1 = fminf(colacc1, __shfl_xor(colacc1, 32));
    if (g == 0) {
      atomicMin(&minbuf[colset + b * NPTS + colbase + l31], f2ord(m0));
      atomicMin(&minbuf[colset + b * NPTS + colbase + 32 + l31], f2ord(m1));
    }
  }
}

__global__ __launch_bounds__(TPB) void finalize_kernel(
    const unsigned* __restrict__ minbuf, float* __restrict__ out, float scale) {
  int idx = blockIdx.x * TPB + threadIdx.x;   // 0 .. 2*TOTAL-1
  float v = ord2f(minbuf[idx]) * scale;
  for (int off = 32; off > 0; off >>= 1) v += __shfl_down(v, off);
  __shared__ float ls[TPB / 64];
  if ((threadIdx.x & 63) == 0) ls[threadIdx.x >> 6] = v;
  __syncthreads();
  if (threadIdx.x == 0) {
    float t = 0.0f;
#pragma unroll
    for (int w = 0; w < TPB / 64; ++w) t += ls[w];
    atomicAdd(out, t);
  }
}

extern "C" void kernel_launch(void* const* d_in, const int* in_sizes, int n_in,
                              void* d_out, int out_size, void* d_ws, size_t ws_size,
                              hipStream_t stream) {
  const float* xyz1 = (const float*)d_in[0];
  const float* xyz2 = (const float*)d_in[1];
  float* out = (float*)d_out;

  char* ws = (char*)d_ws;
  unsigned short* Af = (unsigned short*)(ws);
  unsigned short* Bf = (unsigned short*)(ws + (size_t)2 * TOTAL * 32);
  unsigned*   minbuf = (unsigned*)(ws + (size_t)4 * TOTAL * 32);

  // 1) pack A/B forms for both sets (tile-major lane order) + init minbuf
  pack_kernel<<<dim3(2 * TOTAL / TPB), dim3(TPB), 0, stream>>>(
      xyz1, xyz2, Af, Bf, minbuf, out);

  // 2) both directions, col-min only: 32 x 16 x 8 = 4096 blocks
  dim3 mgrid(NPTS / COLS_PER_BLOCK, ROWCH, 2 * BATCH);
  min_kernel<<<mgrid, dim3(TPB), 0, stream>>>(Af, Bf, minbuf);

  // 3) finalize: mean(dist1) + mean(dist2)
  const float scale = 1.0f / (float)TOTAL;
  finalize_kernel<<<dim3(2 * TOTAL / TPB), dim3(TPB), 0, stream>>>(minbuf, out, scale);
}

// Round 24
// 30.827 us; speedup vs baseline: 1.0385x; 1.0037x over previous
//
#include <hip/hip_runtime.h>
#include <math.h>

#define BATCH 4
#define NPTS  8192
#define TOTAL (BATCH * NPTS)            // 32768 points per set
#define TPB   256

#define CT     2                        // fixed col-tiles per wave (32 cols each)
#define WPB    (TPB / 64)               // 4 waves per block
#define COLS_PER_WAVE  (32 * CT)        // 64
#define COLS_PER_BLOCK (COLS_PER_WAVE * WPB)  // 256
#define ROWCH  16                       // swept-row chunks
#define SWEEP  (NPTS / ROWCH)           // 512 rows swept per wave
#define NT     (SWEEP / 32)             // 16 A-tiles per sweep

typedef __bf16 bf16v8 __attribute__((ext_vector_type(8)));
typedef float  f32x16 __attribute__((ext_vector_type(16)));

// ws layout (TILE-MAJOR, MFMA-LANE-ORDER packing; tile = 512 ushorts = 1KB):
//   Af: ushort[2*TOTAL*16] @ 0    (2 MB)  set1 then set2
//   Bf: ushort[2*TOTAL*16] @ 2 MB (2 MB)  same layout
//   minbuf: uint[2*TOTAL]  @ 4 MB (256 KB) dist1 then dist2
//
// FINAL (R24 = R20 champion, 30.63 us measured):
//  - MFMA formulation: 13-slot bf16 hi/lo split K-vectors; one
//    mfma_f32_32x32x16_bf16 computes full fp32 distances for a 32x32 tile
//    (norms + cross terms). absmax 0 vs reference since R4.
//  - Col-min-only: per-lane coltree = min over rows; both Chamfer
//    directions via operand-role swap (blockIdx.z). No rowacc, no
//    butterfly, no LDS in the sweep, one masked atomic per col-tile.
//  - NOTE (R23 lesson): do NOT read MFMA VGPR dests from inline asm --
//    the hazard recognizer doesn't pad INLINEASM reads (absmax 8.5e22).
//    IEEE-mode fminf chains are the correct/safe fold at source level.
//  - Plateau evidence (R10 reps=4 counters): MfmaUtil 45% + VALUBusy 54%
//    = 99% -> SIMD issue saturated; 11 structural variants all within 5%.

__device__ __forceinline__ unsigned f2ord(float f) {
  unsigned b = __float_as_uint(f);
  return ((int)b >= 0) ? (b ^ 0x80000000u) : ~b;
}
__device__ __forceinline__ float ord2f(unsigned k) {
  unsigned b = (k & 0x80000000u) ? (k ^ 0x80000000u) : ~k;
  return __uint_as_float(b);
}
__device__ __forceinline__ unsigned short f2bf(float f) {   // RNE
  unsigned u = __float_as_uint(f);
  return (unsigned short)((u + 0x7fffu + ((u >> 16) & 1u)) >> 16);
}
__device__ __forceinline__ float bf2f(unsigned short h) {
  return __uint_as_float(((unsigned)h) << 16);
}
__device__ __forceinline__ float mf3(float a, float b, float c) {
  return fminf(fminf(a, b), c);
}
// min over 16 acc elements folded with carry-in
__device__ __forceinline__ float coltree(const f32x16& a, float colt) {
  float t0 = mf3(a[0], a[1], a[2]);
  float t1 = mf3(a[3], a[4], a[5]);
  float t2 = mf3(a[6], a[7], a[8]);
  float t3 = mf3(a[9], a[10], a[11]);
  float t4 = mf3(a[12], a[13], a[14]);
  return mf3(colt, mf3(t0, t1, a[15]), mf3(t2, t3, t4));
}

// K-slot pairing (A[k]*B[k]), verified absmax 0 since R4:
//  k0-2: ah*ch   k3-5: al*ch   k6-8: ah*cl   (c = -2b)
//  k9,10: sq_a{h,l} * 1,1      k11,12: 1,1 * sq_b{h,l}     k13-15: 0
__global__ __launch_bounds__(TPB) void pack_kernel(
    const float* __restrict__ x1, const float* __restrict__ x2,
    unsigned short* __restrict__ Af, unsigned short* __restrict__ Bf,
    unsigned* __restrict__ minbuf, float* __restrict__ out) {
  int i = blockIdx.x * TPB + threadIdx.x;   // 0 .. 2*TOTAL-1  (set-major)
  if (i == 0) out[0] = 0.0f;
  minbuf[i] = 0xFFFFFFFFu;

  bool s2 = (i >= TOTAL);
  int j = s2 ? i - TOTAL : i;
  const float* src = s2 ? x2 : x1;
  float x = src[3 * j + 0];
  float y = src[3 * j + 1];
  float z = src[3 * j + 2];
  float sq = fmaf(x, x, fmaf(y, y, z * z));
  unsigned short sh = f2bf(sq);
  unsigned short sl = f2bf(sq - bf2f(sh));
  const unsigned short one = 0x3F80;

  unsigned short hx = f2bf(x), hy = f2bf(y), hz = f2bf(z);
  unsigned short lx = f2bf(x - bf2f(hx)), ly = f2bf(y - bf2f(hy)), lz = f2bf(z - bf2f(hz));
  float cx = -2.0f * x, cy = -2.0f * y, cz = -2.0f * z;
  unsigned short chx = f2bf(cx), chy = f2bf(cy), chz = f2bf(cz);
  unsigned short clx = f2bf(cx - bf2f(chx)), cly = f2bf(cy - bf2f(chy)), clz = f2bf(cz - bf2f(chz));

  // tile-major lane-order offsets (ushort units), tile stride 512:
  size_t o0 = (size_t)(i >> 5) * 512 + (size_t)(i & 31) * 8;
  size_t o1 = o0 + 256;

  // A-form
  {
    unsigned short v[16] = {hx, hy, hz, lx, ly, lz, hx, hy, hz,
                            sh, sl, one, one, 0, 0, 0};
    uint4 w0, w1;
    w0.x = v[0] | ((unsigned)v[1] << 16);  w0.y = v[2] | ((unsigned)v[3] << 16);
    w0.z = v[4] | ((unsigned)v[5] << 16);  w0.w = v[6] | ((unsigned)v[7] << 16);
    w1.x = v[8] | ((unsigned)v[9] << 16);  w1.y = v[10] | ((unsigned)v[11] << 16);
    w1.z = v[12] | ((unsigned)v[13] << 16); w1.w = v[14] | ((unsigned)v[15] << 16);
    *(uint4*)(Af + o0) = w0;
    *(uint4*)(Af + o1) = w1;
  }
  // B-form
  {
    unsigned short v[16] = {chx, chy, chz, chx, chy, chz, clx, cly, clz,
                            one, one, sh, sl, 0, 0, 0};
    uint4 w0, w1;
    w0.x = v[0] | ((unsigned)v[1] << 16);  w0.y = v[2] | ((unsigned)v[3] << 16);
    w0.z = v[4] | ((unsigned)v[5] << 16);  w0.w = v[6] | ((unsigned)v[7] << 16);
    w1.x = v[8] | ((unsigned)v[9] << 16);  w1.y = v[10] | ((unsigned)v[11] << 16);
    w1.z = v[12] | ((unsigned)v[13] << 16); w1.w = v[14] | ((unsigned)v[15] << 16);
    *(uint4*)(Bf + o0) = w0;
    *(uint4*)(Bf + o1) = w1;
  }
}

// Col-min-only pass, both directions via blockIdx.z.
__global__ __launch_bounds__(TPB, 4) void min_kernel(
    const unsigned short* __restrict__ Af, const unsigned short* __restrict__ Bf,
    unsigned* __restrict__ minbuf) {
  const int z   = blockIdx.z;
  const int b   = z & (BATCH - 1);
  const int dir = z >> 2;
  const int tid = threadIdx.x;
  const int wave = tid >> 6, lane = tid & 63;
  const int g = lane >> 5, l31 = lane & 31;

  const int colset = dir * TOTAL;          // offset of the col (target) set
  const int rowset = TOTAL - colset;       // offset of the swept set
  const int colbase = blockIdx.x * COLS_PER_BLOCK + wave * COLS_PER_WAVE;
  const int rowbase = blockIdx.y * SWEEP;

  // fixed B fragments: CT=2 col-tiles, lane-sequential (tile = 64 bf16v8)
  const int bt0 = (colset + b * NPTS + colbase) >> 5;
  const bf16v8* bvt = (const bf16v8*)Bf;
  bf16v8 bfr0 = bvt[(size_t)bt0 * 64 + lane];
  bf16v8 bfr1 = bvt[(size_t)(bt0 + 1) * 64 + lane];

  f32x16 zc;
#pragma unroll
  for (int q = 0; q < 16; ++q) zc[q] = 0.0f;
  float colacc0 = INFINITY, colacc1 = INFINITY;

  const int at0 = (rowset + b * NPTS + rowbase) >> 5;
  const bf16v8* ap = (const bf16v8*)Af + (size_t)at0 * 64 + lane;

#pragma unroll
  for (int ti = 0; ti < NT; ++ti) {
    bf16v8 a = ap[ti * 64];                // lane-sequential, 1KB contiguous
    f32x16 acc0 = __builtin_amdgcn_mfma_f32_32x32x16_bf16(a, bfr0, zc, 0, 0, 0);
    f32x16 acc1 = __builtin_amdgcn_mfma_f32_32x32x16_bf16(a, bfr1, zc, 0, 0, 0);
    colacc0 = coltree(acc0, colacc0);
    colacc1 = coltree(acc1, colacc1);
  }

  // tail: merge g-halves (rows split across lane>>5), one masked atomic per tile
  {
    float m0 = fminf(colacc0, __shfl_xor(colacc0, 32));
    float m1 = fminf(colacc1, __shfl_xor(colacc1, 32));
    if (g == 0) {
      atomicMin(&minbuf[colset + b * NPTS + colbase + l31], f2ord(m0));
      atomicMin(&minbuf[colset + b * NPTS + colbase + 32 + l31], f2ord(m1));
    }
  }
}

__global__ __launch_bounds__(TPB) void finalize_kernel(
    const unsigned* __restrict__ minbuf, float* __restrict__ out, float scale) {
  int idx = blockIdx.x * TPB + threadIdx.x;   // 0 .. 2*TOTAL-1
  float v = ord2f(minbuf[idx]) * scale;
  for (int off = 32; off > 0; off >>= 1) v += __shfl_down(v, off);
  __shared__ float ls[TPB / 64];
  if ((threadIdx.x & 63) == 0) ls[threadIdx.x >> 6] = v;
  __syncthreads();
  if (threadIdx.x == 0) {
    float t = 0.0f;
#pragma unroll
    for (int w = 0; w < TPB / 64; ++w) t += ls[w];
    atomicAdd(out, t);
  }
}

extern "C" void kernel_launch(void* const* d_in, const int* in_sizes, int n_in,
                              void* d_out, int out_size, void* d_ws, size_t ws_size,
                              hipStream_t stream) {
  const float* xyz1 = (const float*)d_in[0];
  const float* xyz2 = (const float*)d_in[1];
  float* out = (float*)d_out;

  char* ws = (char*)d_ws;
  unsigned short* Af = (unsigned short*)(ws);
  unsigned short* Bf = (unsigned short*)(ws + (size_t)2 * TOTAL * 32);
  unsigned*   minbuf = (unsigned*)(ws + (size_t)4 * TOTAL * 32);

  // 1) pack A/B forms for both sets (tile-major lane order) + init minbuf
  pack_kernel<<<dim3(2 * TOTAL / TPB), dim3(TPB), 0, stream>>>(
      xyz1, xyz2, Af, Bf, minbuf, out);

  // 2) both directions, col-min only: 32 x 16 x 8 = 4096 blocks
  dim3 mgrid(NPTS / COLS_PER_BLOCK, ROWCH, 2 * BATCH);
  min_kernel<<<mgrid, dim3(TPB), 0, stream>>>(Af, Bf, minbuf);

  // 3) finalize: mean(dist1) + mean(dist2)
  const float scale = 1.0f / (float)TOTAL;
  finalize_kernel<<<dim3(2 * TOTAL / TPB), dim3(TPB), 0, stream>>>(minbuf, out, scale);
}